// Round 5
// baseline (618.822 us; speedup 1.0000x reference)
//
#include <hip/hip_runtime.h>

#define S_LEN    2048
#define DK       64
#define N_BH     32
#define ROWS     8
#define NTHREADS 512

typedef float          f32x4  __attribute__((ext_vector_type(4)));
typedef int            i32x4  __attribute__((ext_vector_type(4)));
typedef short          bf16x8 __attribute__((ext_vector_type(8)));
typedef unsigned short u16x8  __attribute__((ext_vector_type(8)));
typedef unsigned short u16x4  __attribute__((ext_vector_type(4)));

__device__ __forceinline__ unsigned short f2bf(float f) {
    unsigned u = __builtin_bit_cast(unsigned, f);
    u += 0x7fffu + ((u >> 16) & 1u);
    return (unsigned short)(u >> 16);
}
__device__ __forceinline__ float bf2f(unsigned short h) {
    unsigned u = ((unsigned)h) << 16;
    return __builtin_bit_cast(float, u);
}

// ---------------- prep kernels (bf16 pre-conversion into d_ws) ----------------
__global__ void prep_qcast(const float* __restrict__ q, unsigned short* __restrict__ Qb) {
    const long i = ((long)blockIdx.x * 256 + threadIdx.x) * 8;
    f32x4 a = *(const f32x4*)(q + i);
    f32x4 b = *(const f32x4*)(q + i + 4);
    u16x8 o;
    o[0]=f2bf(a.x); o[1]=f2bf(a.y); o[2]=f2bf(a.z); o[3]=f2bf(a.w);
    o[4]=f2bf(b.x); o[5]=f2bf(b.y); o[6]=f2bf(b.z); o[7]=f2bf(b.w);
    *(u16x8*)(Qb + i) = o;
}

// k[bh][64][2048] (f32) -> Kb[bh][2048][64] (bf16)
__global__ void prep_k(const float* __restrict__ k, unsigned short* __restrict__ Kb) {
    __shared__ float t[64][65];
    const int bh = blockIdx.x >> 5, s0 = (blockIdx.x & 31) << 6;
    const int tx = threadIdx.x;
    const float* kb = k + (long)bh * 64 * S_LEN;
    #pragma unroll
    for (int i = 0; i < 16; ++i) {
        const int d = (i << 2) + (tx >> 6), s = tx & 63;
        t[d][s] = kb[(long)d * S_LEN + s0 + s];
    }
    __syncthreads();
    #pragma unroll
    for (int i = 0; i < 16; ++i) {
        const int s = (i << 2) + (tx >> 6), d = tx & 63;
        Kb[((long)bh * S_LEN + s0 + s) * DK + d] = f2bf(t[d][s]);
    }
}

// v[bh][2048][64] (f32) -> Vb[bh][64][2048] (bf16)
__global__ void prep_v(const float* __restrict__ v, unsigned short* __restrict__ Vb) {
    __shared__ float t[64][65];
    const int bh = blockIdx.x >> 5, s0 = (blockIdx.x & 31) << 6;
    const int tx = threadIdx.x;
    #pragma unroll
    for (int i = 0; i < 16; ++i) {
        const int s = (i << 2) + (tx >> 6), d = tx & 63;
        t[s][d] = v[((long)bh * S_LEN + s0 + s) * DK + d];
    }
    __syncthreads();
    #pragma unroll
    for (int i = 0; i < 16; ++i) {
        const int d = (i << 2) + (tx >> 6), s = tx & 63;
        Vb[((long)bh * DK + d) * S_LEN + s0 + s] = f2bf(t[s][d]);
    }
}

// ---------------------------- main attention kernel ----------------------------
// e stored in LDS as bf16 (proven numerics), 8 rows x 2048, XOR-swizzled:
// element address = row*2048 + (col ^ (row<<3))
template <bool WS>
__global__ __launch_bounds__(NTHREADS, 8)
void sdpa_main(const float* __restrict__ q, const float* __restrict__ k,
               const float* __restrict__ v, const int* __restrict__ mask,
               const unsigned short* __restrict__ Qb,
               const unsigned short* __restrict__ Kb,
               const unsigned short* __restrict__ Vb,
               float* __restrict__ ctx, float* __restrict__ attn)
{
    extern __shared__ unsigned short elds[];      // [8][2048] bf16 e
    __shared__ float ctxlds[ROWS * DK];           // 8x64
    __shared__ float invlds[ROWS];

    const int bid  = blockIdx.x;
    const int bh   = bid & (N_BH - 1);
    const int qt   = bid >> 5;
    const int tid  = threadIdx.x;
    const int wave = tid >> 6;
    const int lane = tid & 63;
    const int m    = lane & 15;
    const int g    = lane >> 4;
    const int mr   = m & 7;                        // q-row this lane serves (dup for m>=8)
    const long rowbase = (long)bh * S_LEN + qt * ROWS;

    ctxlds[tid] = 0.0f;                            // 512 threads cover 8x64 exactly

    // ===== Phase 1: S^T tile = mfma(K, Q); e = exp(s/8) -> bf16 LDS =====
    {
        bf16x8 qfrag[2];                           // B operand: Q[col=m -> row mr][k]
        if (WS) {
            const unsigned short* qp = Qb + (rowbase + mr) * DK;
            qfrag[0] = *(const bf16x8*)(qp + g * 8);
            qfrag[1] = *(const bf16x8*)(qp + 32 + g * 8);
        } else {
            const float* qp = q + (rowbase + mr) * DK;
            #pragma unroll
            for (int ks = 0; ks < 2; ++ks) {
                const float* p = qp + ks * 32 + g * 8;
                f32x4 x0 = *(const f32x4*)p, x1 = *(const f32x4*)(p + 4);
                qfrag[ks][0]=(short)f2bf(x0.x); qfrag[ks][1]=(short)f2bf(x0.y);
                qfrag[ks][2]=(short)f2bf(x0.z); qfrag[ks][3]=(short)f2bf(x0.w);
                qfrag[ks][4]=(short)f2bf(x1.x); qfrag[ks][5]=(short)f2bf(x1.y);
                qfrag[ks][6]=(short)f2bf(x1.z); qfrag[ks][7]=(short)f2bf(x1.w);
            }
        }
        for (int ct = 0; ct < 16; ++ct) {
            const int t0 = (wave << 8) + (ct << 4);
            const int tk = t0 + m;                 // A operand: K row (t dim)
            f32x4 acc = {0.f, 0.f, 0.f, 0.f};
            #pragma unroll
            for (int ks = 0; ks < 2; ++ks) {
                bf16x8 kfrag;
                if (WS) {
                    kfrag = *(const bf16x8*)(Kb + ((long)bh * S_LEN + tk) * DK + ks * 32 + g * 8);
                } else {
                    const float* kp = k + (long)bh * DK * S_LEN + (long)(ks * 32 + g * 8) * S_LEN + tk;
                    #pragma unroll
                    for (int j = 0; j < 8; ++j) kfrag[j] = (short)f2bf(kp[(long)j * S_LEN]);
                }
                acc = __builtin_amdgcn_mfma_f32_16x16x32_bf16(kfrag, qfrag[ks], acc, 0, 0, 0);
            }
            // acc[i] = S[q=m][t = t0 + 4g + i]; only q-rows 0..7 are real
            if (m < 8) {
                u16x4 w;
                w[0] = f2bf(__expf(acc[0] * 0.125f));
                w[1] = f2bf(__expf(acc[1] * 0.125f));
                w[2] = f2bf(__expf(acc[2] * 0.125f));
                w[3] = f2bf(__expf(acc[3] * 0.125f));
                const int col = (t0 + (g << 2)) ^ (m << 3);    // 4-elem aligned
                *(u16x4*)(elds + m * 2048 + col) = w;
            }
        }
    }
    __syncthreads();

    // ===== Phase 2: mask->zero, row-sum, attn = e*rinv (HBM streaming) =====
    {
        const int r = wave;                        // 8 rows, one wave each
        const int j = lane;
        unsigned short* erow = elds + r * 2048;
        const int sw = r << 3;
        const long arow = (rowbase + r) * (long)S_LEN;
        const int* mrow = mask + arow;
        float rsum = 0.f;
        #pragma unroll
        for (int i = 0; i < 4; ++i) {
            const int t  = (j << 3) + (i << 9);
            const int ts = t ^ sw;
            u16x8 ev = *(u16x8*)(erow + ts);
            i32x4 m0 = __builtin_nontemporal_load((const i32x4*)(mrow + t));
            i32x4 m1 = __builtin_nontemporal_load((const i32x4*)(mrow + t + 4));
            if (m0.x) ev[0] = 0;  if (m0.y) ev[1] = 0;
            if (m0.z) ev[2] = 0;  if (m0.w) ev[3] = 0;
            if (m1.x) ev[4] = 0;  if (m1.y) ev[5] = 0;
            if (m1.z) ev[6] = 0;  if (m1.w) ev[7] = 0;
            *(u16x8*)(erow + ts) = ev;
            rsum += ((bf2f(ev[0]) + bf2f(ev[1])) + (bf2f(ev[2]) + bf2f(ev[3])))
                  + ((bf2f(ev[4]) + bf2f(ev[5])) + (bf2f(ev[6]) + bf2f(ev[7])));
        }
        #pragma unroll
        for (int off = 32; off; off >>= 1) rsum += __shfl_xor(rsum, off);
        const float rinv = 1.0f / rsum;
        if (j == 0) invlds[r] = rinv;
        float* aout = attn + arow;
        #pragma unroll
        for (int i = 0; i < 4; ++i) {
            const int t  = (j << 3) + (i << 9);
            const int ts = t ^ sw;
            u16x8 ev = *(u16x8*)(erow + ts);
            f32x4 o0 = { bf2f(ev[0]) * rinv, bf2f(ev[1]) * rinv,
                         bf2f(ev[2]) * rinv, bf2f(ev[3]) * rinv };
            f32x4 o1 = { bf2f(ev[4]) * rinv, bf2f(ev[5]) * rinv,
                         bf2f(ev[6]) * rinv, bf2f(ev[7]) * rinv };
            __builtin_nontemporal_store(o0, (f32x4*)(aout + t));
            __builtin_nontemporal_store(o1, (f32x4*)(aout + t + 4));
        }
    }
    __syncthreads();

    // ===== Phase 3: ctx = (e @ V) * rinv ; A = bf16 LDS rows (dup for m>=8) =====
    {
        const int d0 = (wave & 3) << 4;
        const int kh = wave >> 2;
        const int sw = mr << 3;
        const unsigned short* arow = elds + mr * 2048;
        f32x4 cacc = {0.f, 0.f, 0.f, 0.f};
        for (int ks = 0; ks < 32; ++ks) {
            const int cb = (kh << 10) + (ks << 5) + (g << 3);
            bf16x8 af = *(const bf16x8*)(arow + (cb ^ sw));
            bf16x8 bfv;
            if (WS) {
                bfv = *(const bf16x8*)(Vb + ((long)bh * DK + d0 + m) * S_LEN + cb);
            } else {
                const float* vp = v + (long)bh * S_LEN * DK + (long)cb * DK + d0 + m;
                #pragma unroll
                for (int j = 0; j < 8; ++j) bfv[j] = (short)f2bf(vp[j * DK]);
            }
            cacc = __builtin_amdgcn_mfma_f32_16x16x32_bf16(af, bfv, cacc, 0, 0, 0);
        }
        if (g < 2) {                               // C rows 0..7 are real
            #pragma unroll
            for (int i = 0; i < 4; ++i)
                atomicAdd(&ctxlds[(4 * g + i) * DK + d0 + m], cacc[i]);
        }
    }
    __syncthreads();

    {
        const int rr = tid >> 6, dd = tid & 63;    // 512 threads = 8x64
        ctx[(rowbase + rr) * DK + dd] = ctxlds[tid] * invlds[rr];
    }
}

extern "C" void kernel_launch(void* const* d_in, const int* in_sizes, int n_in,
                              void* d_out, int out_size, void* d_ws, size_t ws_size,
                              hipStream_t stream)
{
    const float* q    = (const float*)d_in[0];
    const float* k    = (const float*)d_in[1];
    const float* v    = (const float*)d_in[2];
    const int*   mask = (const int*)d_in[3];

    float* ctx  = (float*)d_out;
    float* attn = ctx + (size_t)N_BH * S_LEN * DK;

    const size_t nel = (size_t)N_BH * S_LEN * DK;
    const bool use_ws = ws_size >= nel * 3 * sizeof(unsigned short);
    unsigned short* Qb = (unsigned short*)d_ws;
    unsigned short* Kb = Qb + nel;
    unsigned short* Vb = Kb + nel;

    const size_t shbytes = (size_t)ROWS * 2048 * sizeof(unsigned short);  // 32 KB
    const int nblocks = N_BH * (S_LEN / ROWS);                            // 8192

    if (use_ws) {
        prep_qcast<<<(int)(nel / (256 * 8)), 256, 0, stream>>>(q, Qb);
        prep_k<<<N_BH * (S_LEN / 64), 256, 0, stream>>>(k, Kb);
        prep_v<<<N_BH * (S_LEN / 64), 256, 0, stream>>>(v, Vb);
        (void)hipFuncSetAttribute((const void*)sdpa_main<true>,
                                  hipFuncAttributeMaxDynamicSharedMemorySize, (int)shbytes);
        sdpa_main<true><<<nblocks, NTHREADS, shbytes, stream>>>(q, k, v, mask, Qb, Kb, Vb, ctx, attn);
    } else {
        (void)hipFuncSetAttribute((const void*)sdpa_main<false>,
                                  hipFuncAttributeMaxDynamicSharedMemorySize, (int)shbytes);
        sdpa_main<false><<<nblocks, NTHREADS, shbytes, stream>>>(q, k, v, mask,
                                                                 nullptr, nullptr, nullptr, ctx, attn);
    }
}

// Round 6
// 489.050 us; speedup vs baseline: 1.2654x; 1.2654x over previous
//
#include <hip/hip_runtime.h>

#define S_LEN    2048
#define DK       64
#define N_BH     32
#define ROWS     16
#define NTHREADS 512

typedef float          f32x4  __attribute__((ext_vector_type(4)));
typedef int            i32x4  __attribute__((ext_vector_type(4)));
typedef short          bf16x8 __attribute__((ext_vector_type(8)));
typedef unsigned short u16x8  __attribute__((ext_vector_type(8)));
typedef unsigned int   u32x4  __attribute__((ext_vector_type(4)));

__device__ __forceinline__ unsigned short f2bf(float f) {
    unsigned u = __builtin_bit_cast(unsigned, f);
    u += 0x7fffu + ((u >> 16) & 1u);
    return (unsigned short)(u >> 16);
}
__device__ __forceinline__ float bf2f(unsigned short h) {
    unsigned u = ((unsigned)h) << 16;
    return __builtin_bit_cast(float, u);
}
__device__ __forceinline__ unsigned pack_bf2(float a, float b) {
    return (unsigned)f2bf(a) | ((unsigned)f2bf(b) << 16);
}

// ---------------- prep kernels (bf16 pre-conversion into d_ws) ----------------
__global__ void prep_qcast(const float* __restrict__ q, unsigned short* __restrict__ Qb) {
    const long i = ((long)blockIdx.x * 256 + threadIdx.x) * 8;
    f32x4 a = *(const f32x4*)(q + i);
    f32x4 b = *(const f32x4*)(q + i + 4);
    u16x8 o;
    o[0]=f2bf(a.x); o[1]=f2bf(a.y); o[2]=f2bf(a.z); o[3]=f2bf(a.w);
    o[4]=f2bf(b.x); o[5]=f2bf(b.y); o[6]=f2bf(b.z); o[7]=f2bf(b.w);
    *(u16x8*)(Qb + i) = o;
}

// k[bh][64][2048] (f32) -> Kb[bh][2048][64] (bf16)
__global__ void prep_k(const float* __restrict__ k, unsigned short* __restrict__ Kb) {
    __shared__ float t[64][65];
    const int bh = blockIdx.x >> 5, s0 = (blockIdx.x & 31) << 6;
    const int tx = threadIdx.x;
    const float* kb = k + (long)bh * 64 * S_LEN;
    #pragma unroll
    for (int i = 0; i < 16; ++i) {
        const int d = (i << 2) + (tx >> 6), s = tx & 63;
        t[d][s] = kb[(long)d * S_LEN + s0 + s];
    }
    __syncthreads();
    #pragma unroll
    for (int i = 0; i < 16; ++i) {
        const int s = (i << 2) + (tx >> 6), d = tx & 63;
        Kb[((long)bh * S_LEN + s0 + s) * DK + d] = f2bf(t[d][s]);
    }
}

// v[bh][2048][64] (f32) -> Vb[bh][64][2048] (bf16)
__global__ void prep_v(const float* __restrict__ v, unsigned short* __restrict__ Vb) {
    __shared__ float t[64][65];
    const int bh = blockIdx.x >> 5, s0 = (blockIdx.x & 31) << 6;
    const int tx = threadIdx.x;
    #pragma unroll
    for (int i = 0; i < 16; ++i) {
        const int s = (i << 2) + (tx >> 6), d = tx & 63;
        t[s][d] = v[((long)bh * S_LEN + s0 + s) * DK + d];
    }
    __syncthreads();
    #pragma unroll
    for (int i = 0; i < 16; ++i) {
        const int d = (i << 2) + (tx >> 6), s = tx & 63;
        Vb[((long)bh * DK + d) * S_LEN + s0 + s] = f2bf(t[s][d]);
    }
}

// ---------------------------- main attention kernel ----------------------------
// Flash-style: P kept in registers (packed bf16). No e-LDS, no phase barriers
// around big LDS traffic. Each wave owns a 256-wide t-slice of 16 q-rows.
template <bool WS>
__global__ __launch_bounds__(NTHREADS, 4)
void sdpa_main(const float* __restrict__ q, const float* __restrict__ k,
               const float* __restrict__ v, const int* __restrict__ mask,
               const unsigned short* __restrict__ Qb,
               const unsigned short* __restrict__ Kb,
               const unsigned short* __restrict__ Vb,
               float* __restrict__ ctx, float* __restrict__ attn)
{
    __shared__ float rowsum[ROWS];
    __shared__ float ctxlds[ROWS * DK];

    const int bid  = blockIdx.x;
    const int bh   = bid & (N_BH - 1);         // head-minor for K/V L2 locality
    const int qt   = bid >> 5;
    const int tid  = threadIdx.x;
    const int wave = tid >> 6;
    const int lane = tid & 63;
    const int m    = lane & 15;                // q-row (D col) in MFMA tiles
    const int g    = lane >> 4;                // k-group / D row-group
    const long rowbase = (long)bh * S_LEN + qt * ROWS;

    if (tid < ROWS) rowsum[tid] = 0.0f;
    for (int i = tid; i < ROWS * DK; i += NTHREADS) ctxlds[i] = 0.0f;
    __syncthreads();

    // P[q=m][t = wave*256 + ct*16 + 4g + {0..3}] as packed bf16 pairs
    unsigned P0[16], P1[16];
    float rsum = 0.0f;

    // ===== Phase 1: S^T tile = mfma(K, Q); mask; e = exp(s/8) -> registers =====
    {
        bf16x8 qfrag[2];                       // B operand: Q[col=m][k]
        if (WS) {
            const unsigned short* qp = Qb + (rowbase + m) * DK;
            qfrag[0] = *(const bf16x8*)(qp + g * 8);
            qfrag[1] = *(const bf16x8*)(qp + 32 + g * 8);
        } else {
            const float* qp = q + (rowbase + m) * DK;
            #pragma unroll
            for (int ks = 0; ks < 2; ++ks) {
                const float* p = qp + ks * 32 + g * 8;
                f32x4 x0 = *(const f32x4*)p, x1 = *(const f32x4*)(p + 4);
                qfrag[ks][0]=(short)f2bf(x0.x); qfrag[ks][1]=(short)f2bf(x0.y);
                qfrag[ks][2]=(short)f2bf(x0.z); qfrag[ks][3]=(short)f2bf(x0.w);
                qfrag[ks][4]=(short)f2bf(x1.x); qfrag[ks][5]=(short)f2bf(x1.y);
                qfrag[ks][6]=(short)f2bf(x1.z); qfrag[ks][7]=(short)f2bf(x1.w);
            }
        }
        const int tw = wave << 8;
        const long mrow = (rowbase + m) * (long)S_LEN;
        #pragma unroll
        for (int ct = 0; ct < 16; ++ct) {
            const int t0 = tw + (ct << 4);
            const int tk = t0 + m;             // A operand: K row (t dim)
            const i32x4 mk = *(const i32x4*)(mask + mrow + t0 + (g << 2));
            f32x4 acc = {0.f, 0.f, 0.f, 0.f};
            #pragma unroll
            for (int ks = 0; ks < 2; ++ks) {
                bf16x8 kfrag;
                if (WS) {
                    kfrag = *(const bf16x8*)(Kb + ((long)bh * S_LEN + tk) * DK + ks * 32 + g * 8);
                } else {
                    const float* kp = k + (long)bh * DK * S_LEN + (long)(ks * 32 + g * 8) * S_LEN + tk;
                    #pragma unroll
                    for (int j = 0; j < 8; ++j) kfrag[j] = (short)f2bf(kp[(long)j * S_LEN]);
                }
                acc = __builtin_amdgcn_mfma_f32_16x16x32_bf16(kfrag, qfrag[ks], acc, 0, 0, 0);
            }
            // acc[i] = S[q=m][t = t0 + 4g + i]
            const float e0 = mk.x ? 0.0f : __expf(acc[0] * 0.125f);
            const float e1 = mk.y ? 0.0f : __expf(acc[1] * 0.125f);
            const float e2 = mk.z ? 0.0f : __expf(acc[2] * 0.125f);
            const float e3 = mk.w ? 0.0f : __expf(acc[3] * 0.125f);
            rsum += (e0 + e1) + (e2 + e3);
            P0[ct] = pack_bf2(e0, e1);
            P1[ct] = pack_bf2(e2, e3);
        }
        rsum += __shfl_xor(rsum, 16);
        rsum += __shfl_xor(rsum, 32);          // all 4 g-lanes of row m agree
        if (lane < 16) atomicAdd(&rowsum[lane], rsum);
    }
    __syncthreads();
    const float rinv = 1.0f / rowsum[m];

    // ===== Phase 2: interleaved attn stores (streaming) + PV MFMAs =====
    {
        f32x4 cacc[4] = { {0,0,0,0}, {0,0,0,0}, {0,0,0,0}, {0,0,0,0} };
        const int tw   = wave << 8;
        const int srcA = ((g & 1) << 5) + m;   // source lane for j=0..3 half
        const int srcB = srcA + 16;            // source lane for j=4..7 half
        const int hi   = g >> 1;               // which ct-parity this lane needs
        float* aout = attn + (rowbase + m) * (long)S_LEN;
        #pragma unroll
        for (int kt = 0; kt < 8; ++kt) {
            // ---- attn stores for ct = 2kt, 2kt+1 ----
            #pragma unroll
            for (int h = 0; h < 2; ++h) {
                const int ct = 2 * kt + h;
                const unsigned lo = P0[ct], hp = P1[ct];
                f32x4 o = { bf2f((unsigned short)(lo & 0xFFFF)) * rinv,
                            bf2f((unsigned short)(lo >> 16))    * rinv,
                            bf2f((unsigned short)(hp & 0xFFFF)) * rinv,
                            bf2f((unsigned short)(hp >> 16))    * rinv };
                __builtin_nontemporal_store(o, (f32x4*)(aout + tw + (ct << 4) + (g << 2)));
            }
            // ---- build PV A-frag: lane (m,g) needs P[m][kt*32 + 8g + j], j=0..7 ----
            const unsigned a0e = (unsigned)__shfl((int)P0[2*kt],   srcA);
            const unsigned a0o = (unsigned)__shfl((int)P0[2*kt+1], srcA);
            const unsigned a1e = (unsigned)__shfl((int)P1[2*kt],   srcA);
            const unsigned a1o = (unsigned)__shfl((int)P1[2*kt+1], srcA);
            const unsigned a2e = (unsigned)__shfl((int)P0[2*kt],   srcB);
            const unsigned a2o = (unsigned)__shfl((int)P0[2*kt+1], srcB);
            const unsigned a3e = (unsigned)__shfl((int)P1[2*kt],   srcB);
            const unsigned a3o = (unsigned)__shfl((int)P1[2*kt+1], srcB);
            u32x4 wv = { hi ? a0o : a0e, hi ? a1o : a1e,
                         hi ? a2o : a2e, hi ? a3o : a3e };
            const bf16x8 af = __builtin_bit_cast(bf16x8, wv);
            const int tb = tw + (kt << 5) + (g << 3);
            #pragma unroll
            for (int dt = 0; dt < 4; ++dt) {
                bf16x8 bfv;                    // B operand: V[col=d][k=t]
                if (WS) {
                    bfv = *(const bf16x8*)(Vb + ((long)bh * DK + dt * 16 + m) * S_LEN + tb);
                } else {
                    const float* vp = v + ((long)bh * S_LEN + tb) * DK + dt * 16 + m;
                    #pragma unroll
                    for (int j = 0; j < 8; ++j) bfv[j] = (short)f2bf(vp[j * DK]);
                }
                cacc[dt] = __builtin_amdgcn_mfma_f32_16x16x32_bf16(af, bfv, cacc[dt], 0, 0, 0);
            }
        }
        // D[row=q=4g+i][col=d=dt*16+m] -> partial sums across waves
        #pragma unroll
        for (int dt = 0; dt < 4; ++dt)
            #pragma unroll
            for (int i = 0; i < 4; ++i)
                atomicAdd(&ctxlds[(4 * g + i) * DK + dt * 16 + m], cacc[dt][i]);
    }
    __syncthreads();

    #pragma unroll
    for (int i = tid; i < ROWS * DK; i += NTHREADS) {
        const int rr = i >> 6, dd = i & 63;
        ctx[(rowbase + rr) * DK + dd] = ctxlds[i] / rowsum[rr];
    }
}

extern "C" void kernel_launch(void* const* d_in, const int* in_sizes, int n_in,
                              void* d_out, int out_size, void* d_ws, size_t ws_size,
                              hipStream_t stream)
{
    const float* q    = (const float*)d_in[0];
    const float* k    = (const float*)d_in[1];
    const float* v    = (const float*)d_in[2];
    const int*   mask = (const int*)d_in[3];

    float* ctx  = (float*)d_out;
    float* attn = ctx + (size_t)N_BH * S_LEN * DK;

    const size_t nel = (size_t)N_BH * S_LEN * DK;
    const bool use_ws = ws_size >= nel * 3 * sizeof(unsigned short);
    unsigned short* Qb = (unsigned short*)d_ws;
    unsigned short* Kb = Qb + nel;
    unsigned short* Vb = Kb + nel;

    const int nblocks = N_BH * (S_LEN / ROWS);                 // 4096

    if (use_ws) {
        prep_qcast<<<(int)(nel / (256 * 8)), 256, 0, stream>>>(q, Qb);
        prep_k<<<N_BH * (S_LEN / 64), 256, 0, stream>>>(k, Kb);
        prep_v<<<N_BH * (S_LEN / 64), 256, 0, stream>>>(v, Vb);
        sdpa_main<true><<<nblocks, NTHREADS, 0, stream>>>(q, k, v, mask, Qb, Kb, Vb, ctx, attn);
    } else {
        sdpa_main<false><<<nblocks, NTHREADS, 0, stream>>>(q, k, v, mask,
                                                           nullptr, nullptr, nullptr, ctx, attn);
    }
}